// Round 4
// baseline (3521.970 us; speedup 1.0000x reference)
//
#include <hip/hip_runtime.h>
#include <math.h>

// Problem constants
#define Bq 1024
#define Dd 512
#define Nn 131072
#define Kk 16
#define Mm 32  // candidates rescored in f64 per row

// Phase-1 tiling: block owns BM rows x CHUNK cols, as NSUB sub-tiles of BM x BNS.
#define BM   128
#define BNS  128
#define NSUB 8
#define BK   32
#define CHUNK (BNS * NSUB)      // 1024 cols per block
#define NCH   (Nn / CHUNK)      // 128 chunks
#define CPR   (NCH * Kk)        // 2048 candidates per row

// Output layout (flat concat, reference return order)
#define OUT_SC  0
#define OUT_IDX (Bq * Kk)                 // 16384
#define OUT_SEQ (2 * Bq * Kk)             // 32768
#define OUT_LAB (2 * Bq * Kk + Bq * Kk * Dd)  // 8421376

// ---------------------------------------------------------------------------
// Kernel 1: L2-normalize queries (fp32; pass-1 candidate selection only).
// ---------------------------------------------------------------------------
__global__ __launch_bounds__(256) void k_norm(const float* __restrict__ q,
                                              float* __restrict__ qn) {
  const int row = blockIdx.x;
  const int t = threadIdx.x;
  const float* qr = q + row * Dd;
  float v0 = qr[t];
  float v1 = qr[t + 256];
  float ss = v0 * v0 + v1 * v1;
#pragma unroll
  for (int m = 32; m >= 1; m >>= 1) ss += __shfl_xor(ss, m);
  __shared__ float wsum[4];
  if ((t & 63) == 0) wsum[t >> 6] = ss;
  __syncthreads();
  const float inv = rsqrtf(wsum[0] + wsum[1] + wsum[2] + wsum[3]);
  qn[row * Dd + t] = v0 * inv;
  qn[row * Dd + t + 256] = v1 * inv;
}

// ---------------------------------------------------------------------------
// Kernel 2: fused sims + exact per-(row,1024-col-chunk) top-16 (fp32).
// FIXED: all argmax/argmin butterflies now use a strict total order with lane
// id as final tie-break, guaranteeing convergence to a UNIQUE winner lane.
// (Previous all-equal tie case left every lane thinking it won -> all 16
// lanes inserted the same candidate -> per-chunk list = 16 copies of max.)
// ---------------------------------------------------------------------------
__global__ __launch_bounds__(256, 4) void k_simtopk(
    const float* __restrict__ qn, const float* __restrict__ w,
    float* __restrict__ cs, int* __restrict__ ci) {
  __shared__ float As[BK][BM];   // 16 KB, k-major
  __shared__ float Bs[BK][BNS];  // 16 KB, k-major (matches global layout)

  const int t = threadIdx.x;
  const int cg = t & 15;
  const int rg = t >> 4;
  const int gl = cg;
  const int row0 = blockIdx.x * BM;
  const int nbase = blockIdx.y * CHUNK;

  float top_s[8];
  int top_i[8];
#pragma unroll
  for (int i = 0; i < 8; i++) { top_s[i] = -INFINITY; top_i[i] = 0x7fffffff; }

  for (int sub = 0; sub < NSUB; sub++) {
    const int n0 = nbase + sub * BNS;
    float acc[8][8];
#pragma unroll
    for (int i = 0; i < 8; i++)
#pragma unroll
      for (int j = 0; j < 8; j++) acc[i][j] = 0.0f;

    for (int kt = 0; kt < Dd / BK; kt++) {
      __syncthreads();
      {  // stage A: 128 rows x 32 k
        const int r = t >> 1;
        const int k0 = (t & 1) * 16;
        const float* s = qn + (row0 + r) * Dd + kt * BK + k0;
        float4 a0 = ((const float4*)s)[0];
        float4 a1 = ((const float4*)s)[1];
        float4 a2 = ((const float4*)s)[2];
        float4 a3 = ((const float4*)s)[3];
        float av[16] = {a0.x, a0.y, a0.z, a0.w, a1.x, a1.y, a1.z, a1.w,
                        a2.x, a2.y, a2.z, a2.w, a3.x, a3.y, a3.z, a3.w};
#pragma unroll
        for (int j = 0; j < 16; j++) As[k0 + j][r] = av[j];
      }
      {  // stage B: 32 k x 128 cols, coalesced
        const int kk = t >> 3;
        const int c0 = (t & 7) * 16;
        const float* s = w + (kt * BK + kk) * Nn + n0 + c0;
        float4 b0 = ((const float4*)s)[0];
        float4 b1 = ((const float4*)s)[1];
        float4 b2 = ((const float4*)s)[2];
        float4 b3 = ((const float4*)s)[3];
        *(float4*)&Bs[kk][c0 + 0] = b0;
        *(float4*)&Bs[kk][c0 + 4] = b1;
        *(float4*)&Bs[kk][c0 + 8] = b2;
        *(float4*)&Bs[kk][c0 + 12] = b3;
      }
      __syncthreads();
#pragma unroll
      for (int k = 0; k < BK; k++) {
        float4 a0 = *(const float4*)&As[k][rg * 8];
        float4 a1 = *(const float4*)&As[k][rg * 8 + 4];
        float4 b0 = *(const float4*)&Bs[k][cg * 8];
        float4 b1 = *(const float4*)&Bs[k][cg * 8 + 4];
        float av[8] = {a0.x, a0.y, a0.z, a0.w, a1.x, a1.y, a1.z, a1.w};
        float bv[8] = {b0.x, b0.y, b0.z, b0.w, b1.x, b1.y, b1.z, b1.w};
#pragma unroll
        for (int i = 0; i < 8; i++)
#pragma unroll
          for (int j = 0; j < 8; j++)
            acc[i][j] = fmaf(av[i], bv[j], acc[i][j]);
      }
    }

    // Merge sub-tile into per-row running top-16 (exact extraction).
#pragma unroll
    for (int s8 = 0; s8 < 8; s8++) {
      float lm = acc[s8][0];
      int lj = 0;
#pragma unroll
      for (int j = 1; j < 8; j++)
        if (acc[s8][j] > lm) { lm = acc[s8][j]; lj = j; }
#pragma unroll 1
      for (int iter = 0; iter < 160; iter++) {
        // group argmax of remaining (order: score desc, index asc, lane asc)
        float s = lm;
        int si = n0 + cg * 8 + lj;
        int sl = gl;
#pragma unroll
        for (int m = 8; m >= 1; m >>= 1) {
          float so = __shfl_xor(s, m);
          int io = __shfl_xor(si, m);
          int lo = __shfl_xor(sl, m);
          if (so > s || (so == s && (io < si || (io == si && lo < sl)))) {
            s = so; si = io; sl = lo;
          }
        }
        if (s == -INFINITY) break;
        // group argmin of top list (order: score asc, index desc, lane asc)
        float ms = top_s[s8];
        int mi = top_i[s8];
        int ml = gl;
#pragma unroll
        for (int m = 8; m >= 1; m >>= 1) {
          float mso = __shfl_xor(ms, m);
          int mio = __shfl_xor(mi, m);
          int mlo = __shfl_xor(ml, m);
          if (mso < ms || (mso == ms && (mio > mi || (mio == mi && mlo < ml)))) {
            ms = mso; mi = mio; ml = mlo;
          }
        }
        if (!(s > ms || (s == ms && si < mi))) break;
        if (gl == ml) { top_s[s8] = s; top_i[s8] = si; }
        if (gl == sl) {
#pragma unroll
          for (int j = 0; j < 8; j++)
            if (j == lj) acc[s8][j] = -INFINITY;
          lm = acc[s8][0];
          lj = 0;
#pragma unroll
          for (int j = 1; j < 8; j++)
            if (acc[s8][j] > lm) { lm = acc[s8][j]; lj = j; }
        }
      }
    }
  }

#pragma unroll
  for (int s8 = 0; s8 < 8; s8++) {
    const int row = row0 + rg * 8 + s8;
    const int o = row * CPR + blockIdx.y * Kk + gl;
    cs[o] = top_s[s8];
    ci[o] = top_i[s8];
  }
}

// ---------------------------------------------------------------------------
// Kernel 3: per row — wave 0 extracts top-32 from LDS; per-wave f64 norm;
// waves rescore 8 candidates each in f64; wave 0 sorted top-16; gather.
// Butterflies use lane-id final tie-break (strict total order).
// All global-indexing values masked with &(Nn-1): can't fault.
// ---------------------------------------------------------------------------
__global__ __launch_bounds__(256) void k_final(
    const float* __restrict__ cs, const int* __restrict__ ci,
    const float* __restrict__ label, const float* __restrict__ w,
    const float* __restrict__ q, float* __restrict__ out) {
  const int row = blockIdx.x;
  const int t = threadIdx.x;
  const int lane = t & 63;
  const int wv = t >> 6;

  __shared__ float shs[CPR];     // 8 KB
  __shared__ int shi[CPR];       // 8 KB
  __shared__ int sel[Mm];
  __shared__ double resc[Mm];
  __shared__ int sel16[Kk];

  // ---- load candidates into LDS ----
#pragma unroll
  for (int j = 0; j < CPR / 256; j++) {
    const int c = j * 256 + t;
    shs[c] = cs[row * CPR + c];
    shi[c] = ci[row * CPR + c] & (Nn - 1);
  }
  __syncthreads();

  // ---- stage 1: wave 0 extracts top-32 (exact) ----
  if (t < 64) {
    const int seg = t * (CPR / 64);  // 32 candidates per lane
    float bs = -INFINITY;
    int bi = 0x7fffffff;
    int bp = seg;
    for (int p = seg; p < seg + CPR / 64; p++) {
      const float v = shs[p];
      const int ix = shi[p];
      if (v > bs || (v == bs && ix < bi)) { bs = v; bi = ix; bp = p; }
    }
#pragma unroll 1
    for (int it = 0; it < Mm; it++) {
      float s = bs;
      int si = bi;
      int sl = t;
#pragma unroll
      for (int mk = 32; mk >= 1; mk >>= 1) {
        const float so = __shfl_xor(s, mk);
        const int io = __shfl_xor(si, mk);
        const int lo = __shfl_xor(sl, mk);
        if (so > s || (so == s && (io < si || (io == si && lo < sl)))) {
          s = so; si = io; sl = lo;
        }
      }
      if (t == 0) sel[it] = si & (Nn - 1);
      if (t == sl) {
        shs[bp] = -INFINITY;
        bs = -INFINITY;
        bi = 0x7fffffff;
        bp = seg;
        for (int p = seg; p < seg + CPR / 64; p++) {
          const float v = shs[p];
          const int ix = shi[p];
          if (v > bs || (v == bs && ix < bi)) { bs = v; bi = ix; bp = p; }
        }
      }
    }
  }
  __syncthreads();

  // ---- stage 2: per-lane f64 q-slice + per-wave redundant norm ----
  double qd[8];
#pragma unroll
  for (int j = 0; j < 8; j++) qd[j] = (double)q[row * Dd + lane * 8 + j];
  double nn = 0.0;
#pragma unroll
  for (int j = 0; j < 8; j++) nn += qd[j] * qd[j];
#pragma unroll
  for (int mk = 32; mk >= 1; mk >>= 1) nn += __shfl_xor(nn, mk);
  const double nrm = sqrt(nn);

  // ---- stage 3: wave wv rescores candidates wv*8..+8 in f64 ----
#pragma unroll 1
  for (int i = 0; i < Mm / 4; i++) {
    const int c = wv * (Mm / 4) + i;
    const int idx = sel[c];
    double d = 0.0;
#pragma unroll
    for (int j = 0; j < 8; j++)
      d += qd[j] * (double)w[(size_t)(lane * 8 + j) * Nn + idx];
#pragma unroll
    for (int mk = 32; mk >= 1; mk >>= 1) d += __shfl_xor(d, mk);
    if (lane == 0) resc[c] = d / nrm;
  }
  __syncthreads();

  // ---- stage 4: wave 0: sorted top-16 of 32 f64 scores ----
  float* out_sc = out + OUT_SC;
  float* out_ix = out + OUT_IDX;
  float* out_sq = out + OUT_SEQ;
  float* out_lb = out + OUT_LAB;
  if (t < 64) {
    double s = (t < Mm) ? resc[t] : -INFINITY;
    int ix = (t < Mm) ? sel[t] : 0x7fffffff;
#pragma unroll 1
    for (int it = 0; it < Kk; it++) {
      double bs2 = s;
      int bi2 = ix;
      int bl = t;
#pragma unroll
      for (int mk = 32; mk >= 1; mk >>= 1) {
        const double so = __shfl_xor(bs2, mk);
        const int io = __shfl_xor(bi2, mk);
        const int lo = __shfl_xor(bl, mk);
        if (so > bs2 || (so == bs2 && (io < bi2 || (io == bi2 && lo < bl)))) {
          bs2 = so; bi2 = io; bl = lo;
        }
      }
      if (t == 0) {
        const int safe = bi2 & (Nn - 1);
        out_sc[row * Kk + it] = (float)bs2;
        out_ix[row * Kk + it] = (float)bi2;
        out_lb[row * Kk + it] = label[safe];
        sel16[it] = safe;
      }
      if (t == bl) { s = -INFINITY; ix = 0x7fffffff; }
    }
  }
  __syncthreads();

  // ---- stage 5: gather the 16 winning weight columns ----
#pragma unroll 1
  for (int j = 0; j < Kk; j++) {
    const int idx = sel16[j];
    out_sq[(size_t)(row * Kk + j) * Dd + t] = w[(size_t)t * Nn + idx];
    out_sq[(size_t)(row * Kk + j) * Dd + t + 256] =
        w[(size_t)(t + 256) * Nn + idx];
  }
}

// ---------------------------------------------------------------------------
extern "C" void kernel_launch(void* const* d_in, const int* in_sizes, int n_in,
                              void* d_out, int out_size, void* d_ws,
                              size_t ws_size, hipStream_t stream) {
  const float* q = (const float*)d_in[0];
  const float* w = (const float*)d_in[1];
  const float* lab = (const float*)d_in[2];
  float* out = (float*)d_out;

  // workspace: qn (2 MB) | cand scores (8 MB) | cand idx (8 MB)
  float* qn = (float*)d_ws;
  float* cs = qn + (size_t)Bq * Dd;
  int* ci = (int*)(cs + (size_t)Bq * CPR);

  k_norm<<<Bq, 256, 0, stream>>>(q, qn);
  k_simtopk<<<dim3(Bq / BM, NCH), 256, 0, stream>>>(qn, w, cs, ci);
  k_final<<<Bq, 256, 0, stream>>>(cs, ci, lab, w, q, out);
}